// Round 2
// baseline (464.837 us; speedup 1.0000x reference)
//
#include <hip/hip_runtime.h>
#include <stdint.h>

typedef __bf16 bf16x8 __attribute__((ext_vector_type(8)));
typedef float  f32x4  __attribute__((ext_vector_type(4)));
typedef float  f32x8  __attribute__((ext_vector_type(8)));

__device__ __forceinline__ unsigned short f2bf(float f) {
    union { float f; unsigned int u; } v; v.f = f;
    unsigned int u = v.u;
    return (unsigned short)((u + 0x7FFFu + ((u >> 16) & 1u)) >> 16);
}

// ---------------------------------------------------------------------------
// Kernel 1: FWHT each row of W (len 2048), scale 1/sqrt(2048), emit bf16.
// H is symmetric+orthogonal: (xH/vn) W^T == x (W H/vn)^T, so transforming
// W's 2048 rows replaces transforming x's 16384 rows.
// ---------------------------------------------------------------------------
__global__ void fwht_w_kernel(const float* __restrict__ W,
                              unsigned short* __restrict__ Bt) {
    const int n = 2048;
    __shared__ float buf[2048];
    const float* src = W + (size_t)blockIdx.x * n;
    for (int i = threadIdx.x; i < n; i += 256) buf[i] = src[i];
    __syncthreads();
    for (int len = 1; len < n; len <<= 1) {
        for (int j = threadIdx.x; j < n / 2; j += 256) {
            int idx = ((j & ~(len - 1)) << 1) | (j & (len - 1));
            float a = buf[idx], b = buf[idx + len];
            buf[idx]       = a + b;
            buf[idx + len] = a - b;
        }
        __syncthreads();
    }
    const float scale = 0.02209708691207961f; // 1/sqrt(2048)
    unsigned short* dst = Bt + (size_t)blockIdx.x * n;
    for (int i = threadIdx.x; i < n; i += 256) dst[i] = f2bf(buf[i] * scale);
}

// ---------------------------------------------------------------------------
// Kernel 2: C[M][N] = cvt_bf16(A_fp32)[M][K] * B[N][K]^T + bias, fp32 out.
// m97 structure, but A is staged as RAW FP32 via global_load_lds (16 chunks
// of 64x16B for the 128x32 fp32 tile) and converted to bf16 in VALU after
// the ds_read — no separate cast pass over x.
// ---------------------------------------------------------------------------
__global__ __launch_bounds__(256) void had_gemm_kernel(
    const float* __restrict__ A,            // [M][K] fp32 (raw x)
    const unsigned short* __restrict__ B,   // [N][K] bf16 (W')
    const float* __restrict__ bias,         // [N]
    float* __restrict__ C,                  // [M][N] fp32
    int M, int N, int K)
{
    __shared__ __attribute__((aligned(16))) float          Asf[128 * 32]; // 16 KB
    __shared__ __attribute__((aligned(16))) unsigned short Bs[128 * 32];  //  8 KB

    const int tid  = threadIdx.x;
    const int lane = tid & 63;
    const int wave = tid >> 6;
    const int m0 = blockIdx.y * 128;
    const int n0 = blockIdx.x * 128;
    const int wm = (wave & 1) * 64;
    const int wn = (wave >> 1) * 64;
    const int l16  = lane & 15;
    const int quad = lane >> 4;

    f32x4 acc[4][4] = {};

    // A staging: 16 chunks (64 lanes x 16B = 4 floats). chunk u covers
    // floats [u*256, u*256+256): row = u*8 + (lane>>3), col = (lane&7)*4.
    const float* gA[4];
    float* lA[4];
    #pragma unroll
    for (int c = 0; c < 4; ++c) {
        int u = wave * 4 + c;
        int row = u * 8 + (lane >> 3);
        gA[c] = A + (size_t)(m0 + row) * K + (lane & 7) * 4;
        lA[c] = Asf + u * 256;  // wave-uniform base; lane*16B implicit
    }
    // B staging: 8 chunks (64 lanes x 8 bf16). chunk u: row = u*16 +
    // (lane>>2), col = (lane&3)*8.
    const unsigned short* gB[2];
    unsigned short* lB[2];
    #pragma unroll
    for (int c = 0; c < 2; ++c) {
        int u = wave * 2 + c;
        int row = u * 16 + (lane >> 2);
        gB[c] = B + (size_t)(n0 + row) * K + (lane & 3) * 8;
        lB[c] = Bs + u * 512;
    }

    // Fragment pointers. A: fp32, 8 floats = 32B contiguous (2x ds_read_b128).
    const float*          pa = Asf + (wm + l16) * 32 + quad * 8;
    const unsigned short* pb = Bs  + (wn + l16) * 32 + quad * 8;

    for (int k0 = 0; k0 < K; k0 += 32) {
        #pragma unroll
        for (int c = 0; c < 4; ++c)
            __builtin_amdgcn_global_load_lds(
                (__attribute__((address_space(1))) const void*)(gA[c] + k0),
                (__attribute__((address_space(3))) void*)lA[c], 16, 0, 0);
        #pragma unroll
        for (int c = 0; c < 2; ++c)
            __builtin_amdgcn_global_load_lds(
                (__attribute__((address_space(1))) const void*)(gB[c] + k0),
                (__attribute__((address_space(3))) void*)lB[c], 16, 0, 0);
        __syncthreads();

        bf16x8 af[4], bfr[4];
        #pragma unroll
        for (int i = 0; i < 4; ++i) {
            f32x8 a32 = *(const f32x8*)(pa + i * 512);
            bf16x8 r;
            #pragma unroll
            for (int e = 0; e < 8; ++e) r[e] = (__bf16)a32[e];
            af[i] = r;
        }
        #pragma unroll
        for (int j = 0; j < 4; ++j) bfr[j] = *(const bf16x8*)(pb + j * 512);
        #pragma unroll
        for (int i = 0; i < 4; ++i)
            #pragma unroll
            for (int j = 0; j < 4; ++j)
                acc[i][j] = __builtin_amdgcn_mfma_f32_16x16x32_bf16(
                    af[i], bfr[j], acc[i][j], 0, 0, 0);
        __syncthreads();
    }

    // Epilogue: C/D layout col=lane&15, row=quad*4+reg (m89-verified).
    float bv[4];
    #pragma unroll
    for (int j = 0; j < 4; ++j) bv[j] = bias[n0 + wn + j * 16 + l16];

    #pragma unroll
    for (int i = 0; i < 4; ++i) {
        #pragma unroll
        for (int r = 0; r < 4; ++r) {
            int row = m0 + wm + i * 16 + quad * 4 + r;
            float* cp = C + (size_t)row * N + (n0 + wn + l16);
            #pragma unroll
            for (int j = 0; j < 4; ++j)
                cp[j * 16] = acc[i][j][r] + bv[j];
        }
    }
}

// ---------------------------------------------------------------------------
extern "C" void kernel_launch(void* const* d_in, const int* in_sizes, int n_in,
                              void* d_out, int out_size, void* d_ws, size_t ws_size,
                              hipStream_t stream) {
    const float* x = (const float*)d_in[0];  // [4,4096,2048] fp32
    const float* W = (const float*)d_in[1];  // [2048,2048]  fp32
    const float* b = (const float*)d_in[2];  // [2048]       fp32
    float* out = (float*)d_out;              // [4,4096,2048] fp32

    const int d = in_sizes[2];          // 2048
    const int M = in_sizes[0] / d;      // 16384
    const int N = d, K = d;

    // Workspace: W' bf16 [N][K] (8 MB)
    unsigned short* Bt_ws = (unsigned short*)d_ws;

    fwht_w_kernel<<<N, 256, 0, stream>>>(W, Bt_ws);

    dim3 grid(N / 128, M / 128);  // (16, 128)
    had_gemm_kernel<<<grid, 256, 0, stream>>>(x, Bt_ws, b, out, M, N, K);
}

// Round 3
// 390.649 us; speedup vs baseline: 1.1899x; 1.1899x over previous
//
#include <hip/hip_runtime.h>
#include <stdint.h>

typedef __bf16 bf16x8 __attribute__((ext_vector_type(8)));
typedef float  f32x4  __attribute__((ext_vector_type(4)));
typedef unsigned short u16x8 __attribute__((ext_vector_type(8)));

__device__ __forceinline__ unsigned short f2bf(float f) {
    union { float f; unsigned int u; } v; v.f = f;
    unsigned int u = v.u;
    return (unsigned short)((u + 0x7FFFu + ((u >> 16) & 1u)) >> 16);
}

// ---------------------------------------------------------------------------
// Kernel 1: cast x (fp32) -> bf16 A[M][K]. 8 elems/thread, 16B stores.
// ---------------------------------------------------------------------------
__global__ void cast_x_kernel(const float4* __restrict__ X,
                              u16x8* __restrict__ A, int n8) {
    int i = blockIdx.x * blockDim.x + threadIdx.x;
    if (i < n8) {
        float4 v0 = X[i * 2];
        float4 v1 = X[i * 2 + 1];
        u16x8 o;
        o[0] = f2bf(v0.x); o[1] = f2bf(v0.y); o[2] = f2bf(v0.z); o[3] = f2bf(v0.w);
        o[4] = f2bf(v1.x); o[5] = f2bf(v1.y); o[6] = f2bf(v1.z); o[7] = f2bf(v1.w);
        A[i] = o;
    }
}

// ---------------------------------------------------------------------------
// Kernel 2: FWHT each row of W (len 2048), scale 1/sqrt(2048), emit bf16.
// H symmetric+orthogonal: (xH/vn) W^T == x (W H/vn)^T.
// ---------------------------------------------------------------------------
__global__ void fwht_w_kernel(const float* __restrict__ W,
                              unsigned short* __restrict__ Bt) {
    const int n = 2048;
    __shared__ float buf[2048];
    const float* src = W + (size_t)blockIdx.x * n;
    for (int i = threadIdx.x; i < n; i += 256) buf[i] = src[i];
    __syncthreads();
    for (int len = 1; len < n; len <<= 1) {
        for (int j = threadIdx.x; j < n / 2; j += 256) {
            int idx = ((j & ~(len - 1)) << 1) | (j & (len - 1));
            float a = buf[idx], b = buf[idx + len];
            buf[idx]       = a + b;
            buf[idx + len] = a - b;
        }
        __syncthreads();
    }
    const float scale = 0.02209708691207961f; // 1/sqrt(2048)
    unsigned short* dst = Bt + (size_t)blockIdx.x * n;
    for (int i = threadIdx.x; i < n; i += 256) dst[i] = f2bf(buf[i] * scale);
}

// ---------------------------------------------------------------------------
// Kernel 3: C[M][N] = A[M][K]*B[N][K]^T + bias. bf16 MFMA 16x16x32, fp32 out.
// R1 structure upgraded to BK=64 as two 128x32 k-slabs: 32 KB LDS (below the
// m132 64KB occupancy cliff), row stride stays 64 B (bank pattern at floor),
// barrier count halved vs BK=32 -> amortizes the vmcnt(0) drain.
// ---------------------------------------------------------------------------
__global__ __launch_bounds__(256) void had_gemm_kernel(
    const unsigned short* __restrict__ A,   // [M][K] bf16
    const unsigned short* __restrict__ B,   // [N][K] bf16 (W')
    const float* __restrict__ bias,         // [N]
    float* __restrict__ C,                  // [M][N] fp32
    int M, int N, int K)
{
    // [slab][128 rows][32 k], slab s covers k in [k0+32s, k0+32s+32)
    __shared__ __attribute__((aligned(16))) unsigned short As[2][128 * 32];
    __shared__ __attribute__((aligned(16))) unsigned short Bs[2][128 * 32];

    const int tid  = threadIdx.x;
    const int lane = tid & 63;
    const int wave = tid >> 6;
    const int m0 = blockIdx.y * 128;
    const int n0 = blockIdx.x * 128;
    const int wm = (wave & 1) * 64;
    const int wn = (wave >> 1) * 64;
    const int l16  = lane & 15;
    const int quad = lane >> 4;

    f32x4 acc[4][4] = {};

    // Staging: per slab, 8 chunks of (64 lanes x 16 B) = 16 rows x 32 k each.
    // chunk c (0..7): row = c*16 + (lane>>2), k = (lane&3)*8.
    // This wave handles chunks wave*2 + {0,1} of each slab.
    // LDS dest (wave-uniform base + lane*16B) == row-major slab layout since
    // (lane>>2)*32 + (lane&3)*8 == lane*8.  [global_load_lds semantics]
    const int c0 = wave * 2;
    const unsigned short* gA = A + (size_t)(m0 + c0 * 16 + (lane >> 2)) * K + (lane & 3) * 8;
    const unsigned short* gB = B + (size_t)(n0 + c0 * 16 + (lane >> 2)) * K + (lane & 3) * 8;
    const size_t rowStep = (size_t)16 * K;          // chunk c -> c+1
    unsigned short* lA0 = &As[0][c0 * 512];
    unsigned short* lB0 = &Bs[0][c0 * 512];

    // Fragment pointers: A-op layout row=lane&15, k=quad*8+j -> 16B ds_read.
    const unsigned short* pa = &As[0][(wm + l16) * 32 + quad * 8];
    const unsigned short* pb = &Bs[0][(wn + l16) * 32 + quad * 8];

    for (int k0 = 0; k0 < K; k0 += 64) {
        #pragma unroll
        for (int s = 0; s < 2; ++s) {
            #pragma unroll
            for (int c = 0; c < 2; ++c) {
                __builtin_amdgcn_global_load_lds(
                    (__attribute__((address_space(1))) const void*)(gA + k0 + s * 32 + c * rowStep),
                    (__attribute__((address_space(3))) void*)(lA0 + s * 4096 + c * 512), 16, 0, 0);
                __builtin_amdgcn_global_load_lds(
                    (__attribute__((address_space(1))) const void*)(gB + k0 + s * 32 + c * rowStep),
                    (__attribute__((address_space(3))) void*)(lB0 + s * 4096 + c * 512), 16, 0, 0);
            }
        }
        __syncthreads();  // drain vmcnt: staged slabs visible to all waves

        #pragma unroll
        for (int s = 0; s < 2; ++s) {
            bf16x8 af[4], bfr[4];
            #pragma unroll
            for (int i = 0; i < 4; ++i) af[i]  = *(const bf16x8*)(pa + s * 4096 + i * 512);
            #pragma unroll
            for (int j = 0; j < 4; ++j) bfr[j] = *(const bf16x8*)(pb + s * 4096 + j * 512);
            #pragma unroll
            for (int i = 0; i < 4; ++i)
                #pragma unroll
                for (int j = 0; j < 4; ++j)
                    acc[i][j] = __builtin_amdgcn_mfma_f32_16x16x32_bf16(
                        af[i], bfr[j], acc[i][j], 0, 0, 0);
        }
        __syncthreads();  // all waves done reading before next stage
    }

    // Epilogue: C/D layout col=lane&15, row=quad*4+reg (m89-verified).
    float bv[4];
    #pragma unroll
    for (int j = 0; j < 4; ++j) bv[j] = bias[n0 + wn + j * 16 + l16];

    #pragma unroll
    for (int i = 0; i < 4; ++i) {
        #pragma unroll
        for (int r = 0; r < 4; ++r) {
            int row = m0 + wm + i * 16 + quad * 4 + r;
            float* cp = C + (size_t)row * N + (n0 + wn + l16);
            #pragma unroll
            for (int j = 0; j < 4; ++j)
                cp[j * 16] = acc[i][j][r] + bv[j];
        }
    }
}

// ---------------------------------------------------------------------------
extern "C" void kernel_launch(void* const* d_in, const int* in_sizes, int n_in,
                              void* d_out, int out_size, void* d_ws, size_t ws_size,
                              hipStream_t stream) {
    const float* x = (const float*)d_in[0];  // [4,4096,2048] fp32
    const float* W = (const float*)d_in[1];  // [2048,2048]  fp32
    const float* b = (const float*)d_in[2];  // [2048]       fp32
    float* out = (float*)d_out;              // [4,4096,2048] fp32

    const int d = in_sizes[2];          // 2048
    const int M = in_sizes[0] / d;      // 16384
    const int N = d, K = d;

    // Workspace: A bf16 [M][K] (64 MB) + W' bf16 [N][K] (8 MB)
    unsigned short* A_ws  = (unsigned short*)d_ws;
    unsigned short* Bt_ws = A_ws + (size_t)M * K;

    int n8 = in_sizes[0] / 8;
    cast_x_kernel<<<(n8 + 255) / 256, 256, 0, stream>>>(
        (const float4*)x, (u16x8*)A_ws, n8);

    fwht_w_kernel<<<N, 256, 0, stream>>>(W, Bt_ws);

    dim3 grid(N / 128, M / 128);  // (16, 128)
    had_gemm_kernel<<<grid, 256, 0, stream>>>(A_ws, Bt_ws, b, out, M, N, K);
}